// Round 1
// baseline (2746.776 us; speedup 1.0000x reference)
//
#include <hip/hip_runtime.h>
#include <math.h>

#define N_NODES 100000
#define N_EDGES 1600000

// ---------------------------------------------------------------------------
// transform: out[n, 0:COUT]      = x[n,:] @ W[0]
//            out[n, COUT:2COUT]  = x[n,:] @ W[1]
//            out[n, 2COUT:3COUT] = x[n,:] @ root
// C = 3*COUT columns total. W is (2, 64, COUT) row-major, root is (64, COUT).
// W staged in LDS once per block; 8 nodes processed per iteration with
// per-thread accumulators so each W element is read once per 8 nodes.
// ---------------------------------------------------------------------------
template<int C, int COUT>
__global__ void transform_kernel(const float* __restrict__ x,
                                 const float* __restrict__ W,
                                 const float* __restrict__ root,
                                 float* __restrict__ out, int nNodes) {
    constexpr int G = 8;
    __shared__ float sW[64 * C];
    __shared__ float sx[G * 64];

    for (int i = threadIdx.x; i < 2 * 64 * COUT; i += blockDim.x) {
        int k = i / (64 * COUT);
        int r = i % (64 * COUT);
        int f = r / COUT;
        int o = r % COUT;
        sW[f * C + k * COUT + o] = W[i];
    }
    for (int i = threadIdx.x; i < 64 * COUT; i += blockDim.x) {
        int f = i / COUT;
        int o = i % COUT;
        sW[f * C + 2 * COUT + o] = root[i];
    }
    __syncthreads();

    int col = threadIdx.x;
    for (int nbase = blockIdx.x * G; nbase < nNodes; nbase += gridDim.x * G) {
        for (int i = threadIdx.x; i < G * 64; i += blockDim.x) {
            int nl = i >> 6;
            int f  = i & 63;
            int n  = nbase + nl;
            sx[i] = (n < nNodes) ? x[n * 64 + f] : 0.0f;
        }
        __syncthreads();
        if (col < C) {
            float acc[G];
#pragma unroll
            for (int j = 0; j < G; ++j) acc[j] = 0.0f;
            for (int f = 0; f < 64; ++f) {
                float w = sW[f * C + col];
#pragma unroll
                for (int j = 0; j < G; ++j)
                    acc[j] = fmaf(sx[j * 64 + f], w, acc[j]);
            }
#pragma unroll
            for (int j = 0; j < G; ++j) {
                int n = nbase + j;
                if (n < nNodes) out[(size_t)n * C + col] = acc[j];
            }
        }
        __syncthreads();
    }
}

// ---------------------------------------------------------------------------
// edge aggregation, layer 1: F=64 feats, 16 threads/edge, float4 each.
// msg = (1-u)*h0[src] + u*h1[src]; atomicAdd into agg[dst]; also count deg.
// hcat row stride = 192 (h0 at col 0, h1 at col 64).
// ---------------------------------------------------------------------------
__global__ void edge_agg1(const int* __restrict__ ei, const float* __restrict__ ea,
                          const float* __restrict__ hcat, float* __restrict__ agg,
                          float* __restrict__ deg) {
    int gid = blockIdx.x * 256 + threadIdx.x;
    int e   = gid >> 4;
    if (e >= N_EDGES) return;
    int sub = gid & 15;
    int src = ei[e];
    int dst = ei[N_EDGES + e];
    float u = ea[e];
    const float4* h0 = reinterpret_cast<const float4*>(hcat + (size_t)src * 192);
    float4 a = h0[sub];
    float4 b = h0[16 + sub];   // h1 row starts 64 floats (=16 float4) later
    float w0 = 1.0f - u;
    float4 m;
    m.x = w0 * a.x + u * b.x;
    m.y = w0 * a.y + u * b.y;
    m.z = w0 * a.z + u * b.z;
    m.w = w0 * a.w + u * b.w;
    float* o = agg + (size_t)dst * 64 + sub * 4;
    atomicAdd(o + 0, m.x);
    atomicAdd(o + 1, m.y);
    atomicAdd(o + 2, m.z);
    atomicAdd(o + 3, m.w);
    if (sub == 0) atomicAdd(deg + dst, 1.0f);
}

// ---------------------------------------------------------------------------
// edge aggregation, layer 2: F=40 feats, 10 threads/edge, float4 each.
// hcat row stride = 120 (h0 at col 0, h1 at col 40). deg already computed.
// ---------------------------------------------------------------------------
__global__ void edge_agg2(const int* __restrict__ ei, const float* __restrict__ ea,
                          const float* __restrict__ hcat, float* __restrict__ agg) {
    int gid = blockIdx.x * 640 + threadIdx.x;
    int e   = gid / 10;
    if (e >= N_EDGES) return;
    int sub = gid % 10;
    int src = ei[e];
    int dst = ei[N_EDGES + e];
    float u = ea[e];
    const float4* h0 = reinterpret_cast<const float4*>(hcat + (size_t)src * 120);
    float4 a = h0[sub];
    float4 b = h0[10 + sub];   // h1 row starts 40 floats (=10 float4) later
    float w0 = 1.0f - u;
    float4 m;
    m.x = w0 * a.x + u * b.x;
    m.y = w0 * a.y + u * b.y;
    m.z = w0 * a.z + u * b.z;
    m.w = w0 * a.w + u * b.w;
    float* o = agg + (size_t)dst * 40 + sub * 4;
    atomicAdd(o + 0, m.x);
    atomicAdd(o + 1, m.y);
    atomicAdd(o + 2, m.z);
    atomicAdd(o + 3, m.w);
}

// ---------------------------------------------------------------------------
// node epilogue, layer 1: h' = elu(agg/max(deg,1) + x@root1 + b1)
// one thread per (node, feat); hcat stride 192, root part at col 128.
// ---------------------------------------------------------------------------
__global__ void node1_kernel(const float* __restrict__ agg, const float* __restrict__ hcat,
                             const float* __restrict__ b1, const float* __restrict__ deg,
                             float* __restrict__ hpr) {
    int i = blockIdx.x * 256 + threadIdx.x;
    if (i >= N_NODES * 64) return;
    int n = i >> 6;
    int c = i & 63;
    float d = fmaxf(deg[n], 1.0f);
    float v = agg[i] / d + hcat[(size_t)n * 192 + 128 + c] + b1[c];
    hpr[i] = v > 0.0f ? v : expm1f(v);
}

// ---------------------------------------------------------------------------
// node epilogue, layer 2: out = log_softmax(agg/max(deg,1) + h@root2 + b2)
// one thread per node; 40 classes in registers; hcat stride 120, root at 80.
// ---------------------------------------------------------------------------
__global__ void node2_kernel(const float* __restrict__ agg, const float* __restrict__ hcat,
                             const float* __restrict__ b2, const float* __restrict__ deg,
                             float* __restrict__ out) {
    int n = blockIdx.x * 256 + threadIdx.x;
    if (n >= N_NODES) return;
    float dinv = 1.0f / fmaxf(deg[n], 1.0f);
    float v[40];
    float m = -3.4e38f;
#pragma unroll
    for (int c = 0; c < 40; ++c) {
        float t = agg[(size_t)n * 40 + c] * dinv + hcat[(size_t)n * 120 + 80 + c] + b2[c];
        v[c] = t;
        m = fmaxf(m, t);
    }
    float s = 0.0f;
#pragma unroll
    for (int c = 0; c < 40; ++c) s += expf(v[c] - m);
    float lse = m + logf(s);
#pragma unroll
    for (int c = 0; c < 40; ++c) out[(size_t)n * 40 + c] = v[c] - lse;
}

extern "C" void kernel_launch(void* const* d_in, const int* in_sizes, int n_in,
                              void* d_out, int out_size, void* d_ws, size_t ws_size,
                              hipStream_t stream) {
    const float* x     = (const float*)d_in[0];
    const int*   ei    = (const int*)d_in[1];
    const float* ea    = (const float*)d_in[2];
    const float* W1    = (const float*)d_in[3];
    const float* root1 = (const float*)d_in[4];
    const float* b1    = (const float*)d_in[5];
    const float* W2    = (const float*)d_in[6];
    const float* root2 = (const float*)d_in[7];
    const float* b2    = (const float*)d_in[8];
    float* out = (float*)d_out;
    float* ws  = (float*)d_ws;

    // workspace layout (floats):
    float* hcat = ws;                              // N*192 (layer2 reuses as N*120)
    float* agg  = hcat + (size_t)N_NODES * 192;    // N*64  (layer2 reuses as N*40)
    float* hpr  = agg  + (size_t)N_NODES * 64;     // N*64
    float* deg  = hpr  + (size_t)N_NODES * 64;     // N

    // ---- layer 1 ----
    hipMemsetAsync(agg, 0, (size_t)N_NODES * 64 * sizeof(float), stream);
    hipMemsetAsync(deg, 0, (size_t)N_NODES * sizeof(float), stream);
    transform_kernel<192, 64><<<1280, 192, 0, stream>>>(x, W1, root1, hcat, N_NODES);
    edge_agg1<<<N_EDGES * 16 / 256, 256, 0, stream>>>(ei, ea, hcat, agg, deg);
    node1_kernel<<<N_NODES * 64 / 256, 256, 0, stream>>>(agg, hcat, b1, deg, hpr);

    // ---- layer 2 ----
    transform_kernel<120, 40><<<1280, 128, 0, stream>>>(hpr, W2, root2, hcat, N_NODES);
    hipMemsetAsync(agg, 0, (size_t)N_NODES * 40 * sizeof(float), stream);
    edge_agg2<<<N_EDGES * 10 / 640, 640, 0, stream>>>(ei, ea, hcat, agg);
    node2_kernel<<<(N_NODES + 255) / 256, 256, 0, stream>>>(agg, hcat, b2, deg, out);
}

// Round 2
// 558.351 us; speedup vs baseline: 4.9194x; 4.9194x over previous
//
#include <hip/hip_runtime.h>
#include <math.h>

#define N_NODES 100000
#define N_EDGES 1600000
#define NB_SCAN 391  // ceil(N_NODES/256)

// ---------------------------------------------------------------------------
// CSR build: histogram of dst, exclusive scan, scatter (src,u) into buckets.
// ---------------------------------------------------------------------------
__global__ void hist_kernel(const int* __restrict__ ei, int* __restrict__ cnt) {
    int e = blockIdx.x * 256 + threadIdx.x;
    if (e < N_EDGES) atomicAdd(&cnt[ei[N_EDGES + e]], 1);
}

__global__ void scan_block(const int* __restrict__ cnt, int* __restrict__ rowptr,
                           int* __restrict__ bsum) {
    __shared__ int s[256];
    int i = blockIdx.x * 256 + threadIdx.x;
    int v = (i < N_NODES) ? cnt[i] : 0;
    s[threadIdx.x] = v;
    __syncthreads();
    for (int off = 1; off < 256; off <<= 1) {
        int t = (threadIdx.x >= off) ? s[threadIdx.x - off] : 0;
        __syncthreads();
        s[threadIdx.x] += t;
        __syncthreads();
    }
    if (i < N_NODES) rowptr[i] = s[threadIdx.x] - v;  // exclusive within block
    if (threadIdx.x == 255) bsum[blockIdx.x] = s[255];
}

__global__ void scan_total(const int* __restrict__ bsum, int* __restrict__ boff) {
    __shared__ int s[512];
    int t = threadIdx.x;
    s[t] = (t < NB_SCAN) ? bsum[t] : 0;
    __syncthreads();
    for (int off = 1; off < 512; off <<= 1) {
        int v = (t >= off) ? s[t - off] : 0;
        __syncthreads();
        s[t] += v;
        __syncthreads();
    }
    boff[t] = (t == 0) ? 0 : s[t - 1];  // exclusive block offsets
}

__global__ void scan_fix(int* __restrict__ rowptr, const int* __restrict__ boff,
                         int* __restrict__ cur) {
    int i = blockIdx.x * 256 + threadIdx.x;
    if (i >= N_NODES) return;
    int v = rowptr[i] + boff[blockIdx.x];
    rowptr[i] = v;
    cur[i] = v;
}

__global__ void scatter_kernel(const int* __restrict__ ei, const float* __restrict__ ea,
                               int* __restrict__ cur, int* __restrict__ csr_src,
                               float* __restrict__ csr_u) {
    int e = blockIdx.x * 256 + threadIdx.x;
    if (e >= N_EDGES) return;
    int dst = ei[N_EDGES + e];
    int pos = atomicAdd(&cur[dst], 1);
    csr_src[pos] = ei[e];
    csr_u[pos] = ea[e];
}

// ---------------------------------------------------------------------------
// Pull aggregation: one wave per node, lane = feature (64).
// s01[n, 0:64]  = (1/d) * sum_e (1-u_e) feat[src_e]
// s01[n,64:128] = (1/d) * sum_e   u_e   feat[src_e]
// No atomics; coalesced 256B row gathers from L2/L3.
// ---------------------------------------------------------------------------
__global__ __launch_bounds__(256) void pull_agg(
        const int* __restrict__ rowptr, const int* __restrict__ cnt,
        const int* __restrict__ csr_src, const float* __restrict__ csr_u,
        const float* __restrict__ feat, float* __restrict__ s01) {
    int wid  = (blockIdx.x * 256 + threadIdx.x) >> 6;  // node id
    int lane = threadIdx.x & 63;
    if (wid >= N_NODES) return;
    int start = rowptr[wid];
    int deg   = cnt[wid];
    int end   = start + deg;
    float a0 = 0.0f, a1 = 0.0f;
    int i = start;
    for (; i + 1 < end; i += 2) {
        int   sa = csr_src[i];
        int   sb = csr_src[i + 1];
        float ua = csr_u[i];
        float ub = csr_u[i + 1];
        float va = feat[(size_t)sa * 64 + lane];
        float vb = feat[(size_t)sb * 64 + lane];
        a0 = fmaf(1.0f - ua, va, a0);
        a1 = fmaf(ua, va, a1);
        a0 = fmaf(1.0f - ub, vb, a0);
        a1 = fmaf(ub, vb, a1);
    }
    if (i < end) {
        int   sa = csr_src[i];
        float ua = csr_u[i];
        float va = feat[(size_t)sa * 64 + lane];
        a0 = fmaf(1.0f - ua, va, a0);
        a1 = fmaf(ua, va, a1);
    }
    float dinv = 1.0f / fmaxf((float)deg, 1.0f);
    s01[(size_t)wid * 128 + lane]      = a0 * dinv;
    s01[(size_t)wid * 128 + 64 + lane] = a1 * dinv;
}

// ---------------------------------------------------------------------------
// Fused node transform: out[n,:] = act( z[n,:] @ Wcat + bias )
// z = [s01 (128), feat (64)]  (192 inputs);  Wcat = [W0; W1; root] (192 x COUT)
// 4 waves/block, each wave computes 8 nodes; Wcat + z staged in LDS.
// ACT: 1 = ELU, 0 = none.
// ---------------------------------------------------------------------------
template<int COUT, int ACT>
__global__ __launch_bounds__(256) void fused_gemm(
        const float* __restrict__ s01, const float* __restrict__ feat,
        const float* __restrict__ W, const float* __restrict__ root,
        const float* __restrict__ bias, float* __restrict__ out) {
    constexpr int G = 8;
    __shared__ float sW[192 * COUT];
    __shared__ float sz[4][G * 192];

    for (int i = threadIdx.x; i < 128 * COUT; i += 256) sW[i] = W[i];
    for (int i = threadIdx.x; i < 64 * COUT; i += 256) sW[128 * COUT + i] = root[i];
    __syncthreads();

    int wave = threadIdx.x >> 6;
    int lane = threadIdx.x & 63;
    int nbase = (blockIdx.x * 4 + wave) * G;  // grid exactly covers N_NODES

    float* szw = sz[wave];
    for (int i = lane; i < G * 192; i += 64) {
        int j = i / 192;
        int r = i % 192;
        int n = nbase + j;
        szw[i] = (r < 128) ? s01[(size_t)n * 128 + r]
                           : feat[(size_t)n * 64 + (r - 128)];
    }
    __syncthreads();

    int col = lane;
    if (col < COUT) {
        float acc[G];
#pragma unroll
        for (int j = 0; j < G; ++j) acc[j] = 0.0f;
        for (int r = 0; r < 192; ++r) {
            float w = sW[r * COUT + col];
#pragma unroll
            for (int j = 0; j < G; ++j)
                acc[j] = fmaf(szw[j * 192 + r], w, acc[j]);
        }
        float bv = bias[col];
#pragma unroll
        for (int j = 0; j < G; ++j) {
            float v = acc[j] + bv;
            if (ACT == 1) v = (v > 0.0f) ? v : expm1f(v);
            out[(size_t)(nbase + j) * COUT + col] = v;
        }
    }
}

// ---------------------------------------------------------------------------
// In-place log_softmax over 40 classes, one thread per node.
// ---------------------------------------------------------------------------
__global__ void log_softmax_kernel(float* __restrict__ out) {
    int n = blockIdx.x * 256 + threadIdx.x;
    if (n >= N_NODES) return;
    float v[40];
    float m = -3.4e38f;
#pragma unroll
    for (int c = 0; c < 40; ++c) {
        float t = out[(size_t)n * 40 + c];
        v[c] = t;
        m = fmaxf(m, t);
    }
    float s = 0.0f;
#pragma unroll
    for (int c = 0; c < 40; ++c) s += expf(v[c] - m);
    float lse = m + logf(s);
#pragma unroll
    for (int c = 0; c < 40; ++c) out[(size_t)n * 40 + c] = v[c] - lse;
}

extern "C" void kernel_launch(void* const* d_in, const int* in_sizes, int n_in,
                              void* d_out, int out_size, void* d_ws, size_t ws_size,
                              hipStream_t stream) {
    const float* x     = (const float*)d_in[0];
    const int*   ei    = (const int*)d_in[1];
    const float* ea    = (const float*)d_in[2];
    const float* W1    = (const float*)d_in[3];
    const float* root1 = (const float*)d_in[4];
    const float* b1    = (const float*)d_in[5];
    const float* W2    = (const float*)d_in[6];
    const float* root2 = (const float*)d_in[7];
    const float* b2    = (const float*)d_in[8];
    float* out = (float*)d_out;

    // workspace layout
    char* p = (char*)d_ws;
    int*   cnt     = (int*)p;                      p += (size_t)N_NODES * 4;
    int*   rowptr  = (int*)p;                      p += (size_t)N_NODES * 4;
    int*   cur     = (int*)p;                      p += (size_t)N_NODES * 4;
    int*   bsum    = (int*)p;                      p += 512 * 4;
    int*   boff    = (int*)p;                      p += 512 * 4;
    int*   csr_src = (int*)p;                      p += (size_t)N_EDGES * 4;
    float* csr_u   = (float*)p;                    p += (size_t)N_EDGES * 4;
    float* s01     = (float*)p;                    p += (size_t)N_NODES * 128 * 4;
    float* hpr     = (float*)p;                    p += (size_t)N_NODES * 64 * 4;

    // ---- CSR build (shared by both layers) ----
    hipMemsetAsync(cnt, 0, (size_t)N_NODES * 4, stream);
    hist_kernel<<<(N_EDGES + 255) / 256, 256, 0, stream>>>(ei, cnt);
    scan_block<<<NB_SCAN, 256, 0, stream>>>(cnt, rowptr, bsum);
    scan_total<<<1, 512, 0, stream>>>(bsum, boff);
    scan_fix<<<NB_SCAN, 256, 0, stream>>>(rowptr, boff, cur);
    scatter_kernel<<<(N_EDGES + 255) / 256, 256, 0, stream>>>(ei, ea, cur, csr_src, csr_u);

    // ---- layer 1 ----
    pull_agg<<<(N_NODES * 64) / 256, 256, 0, stream>>>(rowptr, cnt, csr_src, csr_u, x, s01);
    fused_gemm<64, 1><<<N_NODES / 32, 256, 0, stream>>>(s01, x, W1, root1, b1, hpr);

    // ---- layer 2 ----
    pull_agg<<<(N_NODES * 64) / 256, 256, 0, stream>>>(rowptr, cnt, csr_src, csr_u, hpr, s01);
    fused_gemm<40, 0><<<N_NODES / 32, 256, 0, stream>>>(s01, hpr, W2, root2, b2, out);
    log_softmax_kernel<<<NB_SCAN, 256, 0, stream>>>(out);
}

// Round 3
// 476.034 us; speedup vs baseline: 5.7701x; 1.1729x over previous
//
#include <hip/hip_runtime.h>
#include <math.h>

#define N_NODES 100000
#define N_EDGES 1600000
#define NB_SCAN 391  // ceil(N_NODES/256)

// ---------------------------------------------------------------------------
// CSR build: histogram of dst, exclusive scan, scatter int2{src,u} records.
// ---------------------------------------------------------------------------
__global__ void hist_kernel(const int* __restrict__ ei, int* __restrict__ cnt) {
    int e = blockIdx.x * 256 + threadIdx.x;
    if (e < N_EDGES) atomicAdd(&cnt[ei[N_EDGES + e]], 1);
}

__global__ void scan_block(const int* __restrict__ cnt, int* __restrict__ rowptr,
                           int* __restrict__ bsum) {
    __shared__ int s[256];
    int i = blockIdx.x * 256 + threadIdx.x;
    int v = (i < N_NODES) ? cnt[i] : 0;
    s[threadIdx.x] = v;
    __syncthreads();
    for (int off = 1; off < 256; off <<= 1) {
        int t = (threadIdx.x >= off) ? s[threadIdx.x - off] : 0;
        __syncthreads();
        s[threadIdx.x] += t;
        __syncthreads();
    }
    if (i < N_NODES) rowptr[i] = s[threadIdx.x] - v;
    if (threadIdx.x == 255) bsum[blockIdx.x] = s[255];
}

__global__ void scan_total(const int* __restrict__ bsum, int* __restrict__ boff) {
    __shared__ int s[512];
    int t = threadIdx.x;
    s[t] = (t < NB_SCAN) ? bsum[t] : 0;
    __syncthreads();
    for (int off = 1; off < 512; off <<= 1) {
        int v = (t >= off) ? s[t - off] : 0;
        __syncthreads();
        s[t] += v;
        __syncthreads();
    }
    boff[t] = (t == 0) ? 0 : s[t - 1];
}

__global__ void scan_fix(int* __restrict__ rowptr, const int* __restrict__ boff,
                         int* __restrict__ cur) {
    int i = blockIdx.x * 256 + threadIdx.x;
    if (i >= N_NODES) return;
    int v = rowptr[i] + boff[blockIdx.x];
    rowptr[i] = v;
    cur[i] = v;
}

__global__ void scatter_kernel(const int* __restrict__ ei, const float* __restrict__ ea,
                               int* __restrict__ cur, int2* __restrict__ rec) {
    int e = blockIdx.x * 256 + threadIdx.x;
    if (e >= N_EDGES) return;
    int dst = ei[N_EDGES + e];
    int pos = atomicAdd(&cur[dst], 1);
    rec[pos] = make_int2(ei[e], __float_as_int(ea[e]));
}

// ---------------------------------------------------------------------------
// Pull aggregation: one wave per node. 16 lanes per edge (float4 over 64
// feats), 4 edges in flight per iteration, shfl_xor cross-group reduce.
// s01[n,0:64] = (1/d)*sum (1-u) feat[src]; s01[n,64:128] = (1/d)*sum u feat[src]
// ---------------------------------------------------------------------------
__global__ __launch_bounds__(256) void pull_agg(
        const int* __restrict__ rowptr, const int* __restrict__ cnt,
        const int2* __restrict__ rec, const float* __restrict__ feat,
        float* __restrict__ s01) {
    int wid  = (blockIdx.x * 256 + threadIdx.x) >> 6;
    int lane = threadIdx.x & 63;
    if (wid >= N_NODES) return;
    int fg = lane & 15;   // float4 index within row
    int eg = lane >> 4;   // edge subgroup 0..3
    int start = rowptr[wid];
    int deg   = cnt[wid];
    int end   = start + deg;
    const float4* f4 = reinterpret_cast<const float4*>(feat);
    float4 a0 = make_float4(0.f, 0.f, 0.f, 0.f);
    float4 a1 = make_float4(0.f, 0.f, 0.f, 0.f);
    for (int i = start + eg; i < end; i += 4) {
        int2 r  = rec[i];
        float u = __int_as_float(r.y);
        float4 v = f4[(size_t)r.x * 16 + fg];
        float w0 = 1.0f - u;
        a0.x = fmaf(w0, v.x, a0.x); a0.y = fmaf(w0, v.y, a0.y);
        a0.z = fmaf(w0, v.z, a0.z); a0.w = fmaf(w0, v.w, a0.w);
        a1.x = fmaf(u, v.x, a1.x);  a1.y = fmaf(u, v.y, a1.y);
        a1.z = fmaf(u, v.z, a1.z);  a1.w = fmaf(u, v.w, a1.w);
    }
    // reduce across the 4 edge subgroups (lanes xor 16, 32)
#define RED4(A)                                             \
    A.x += __shfl_xor(A.x, 16); A.y += __shfl_xor(A.y, 16); \
    A.z += __shfl_xor(A.z, 16); A.w += __shfl_xor(A.w, 16); \
    A.x += __shfl_xor(A.x, 32); A.y += __shfl_xor(A.y, 32); \
    A.z += __shfl_xor(A.z, 32); A.w += __shfl_xor(A.w, 32);
    RED4(a0);
    RED4(a1);
#undef RED4
    float dinv = 1.0f / fmaxf((float)deg, 1.0f);
    float4* o = reinterpret_cast<float4*>(s01) + (size_t)wid * 32;
    if (eg == 0) {
        o[fg] = make_float4(a0.x * dinv, a0.y * dinv, a0.z * dinv, a0.w * dinv);
    } else if (eg == 1) {
        o[16 + fg] = make_float4(a1.x * dinv, a1.y * dinv, a1.z * dinv, a1.w * dinv);
    }
}

// ---------------------------------------------------------------------------
// Node-parallel GEMM: thread = node, all COUT accumulators in registers.
// z = [s01(128) | feat(64)] staged in LDS in 3 chunks of 64, XOR-swizzled
// quads for conflict-free ds_read_b128. Weights are wave-uniform (scalar
// pipe). ACT=1: ELU. ACT=2: fused log_softmax. Coalesced stores via LDS
// transpose.
// ---------------------------------------------------------------------------
template<int COUT, int ACT>
__global__ __launch_bounds__(256) void gemm_node(
        const float* __restrict__ s01, const float* __restrict__ feat,
        const float* __restrict__ W, const float* __restrict__ root,
        const float* __restrict__ bias, float* __restrict__ out) {
    __shared__ float zt[256 * 65];  // 64KB staging area + padded store area
    int tid = threadIdx.x;
    int nbase = blockIdx.x * 256;

    float acc[COUT];
#pragma unroll
    for (int c = 0; c < COUT; ++c) acc[c] = 0.0f;

#pragma unroll
    for (int chunk = 0; chunk < 3; ++chunk) {
        __syncthreads();
        // stage 256 nodes x 64 floats, swizzled quads
        const float* src;
        int stride, off;
        if (chunk < 2) { src = s01; stride = 128; off = chunk * 64; }
        else           { src = feat; stride = 64; off = 0; }
#pragma unroll 4
        for (int it = 0; it < 16; ++it) {
            int flat = it * 256 + tid;
            int n = flat >> 4;
            int g = flat & 15;
            int gn = nbase + n;
            if (gn >= N_NODES) gn = N_NODES - 1;
            float4 v = *reinterpret_cast<const float4*>(src + (size_t)gn * stride + off + 4 * g);
            *reinterpret_cast<float4*>(zt + n * 64 + 4 * (g ^ (n & 7))) = v;
        }
        __syncthreads();
        const float* Wc = (chunk < 2) ? (W + chunk * 64 * COUT) : root;
        for (int rq = 0; rq < 16; ++rq) {
            float4 z = *reinterpret_cast<const float4*>(zt + tid * 64 + 4 * (rq ^ (tid & 7)));
            const float* wr = Wc + rq * 4 * COUT;
#pragma unroll
            for (int k = 0; k < 4; ++k) {
                float zk = (k == 0) ? z.x : (k == 1) ? z.y : (k == 2) ? z.z : z.w;
#pragma unroll
                for (int c = 0; c < COUT; ++c)
                    acc[c] = fmaf(zk, wr[k * COUT + c], acc[c]);
            }
        }
    }

#pragma unroll
    for (int c = 0; c < COUT; ++c) acc[c] += bias[c];

    if (ACT == 1) {
#pragma unroll
        for (int c = 0; c < COUT; ++c)
            acc[c] = (acc[c] > 0.0f) ? acc[c] : expm1f(acc[c]);
    } else {
        float m = acc[0];
#pragma unroll
        for (int c = 1; c < COUT; ++c) m = fmaxf(m, acc[c]);
        float s = 0.0f;
#pragma unroll
        for (int c = 0; c < COUT; ++c) s += expf(acc[c] - m);
        float lse = m + logf(s);
#pragma unroll
        for (int c = 0; c < COUT; ++c) acc[c] -= lse;
    }

    // transpose through LDS for coalesced global stores
    constexpr int P = COUT + 1;
    __syncthreads();
#pragma unroll
    for (int c = 0; c < COUT; ++c) zt[tid * P + c] = acc[c];
    __syncthreads();
    for (int it = 0; it < COUT; ++it) {
        int flat = it * 256 + tid;
        int n = flat / COUT;
        int c = flat - n * COUT;
        int gn = nbase + n;
        if (gn < N_NODES) out[(size_t)gn * COUT + c] = zt[n * P + c];
    }
}

extern "C" void kernel_launch(void* const* d_in, const int* in_sizes, int n_in,
                              void* d_out, int out_size, void* d_ws, size_t ws_size,
                              hipStream_t stream) {
    const float* x     = (const float*)d_in[0];
    const int*   ei    = (const int*)d_in[1];
    const float* ea    = (const float*)d_in[2];
    const float* W1    = (const float*)d_in[3];
    const float* root1 = (const float*)d_in[4];
    const float* b1    = (const float*)d_in[5];
    const float* W2    = (const float*)d_in[6];
    const float* root2 = (const float*)d_in[7];
    const float* b2    = (const float*)d_in[8];
    float* out = (float*)d_out;

    // workspace layout
    char* p = (char*)d_ws;
    int*   cnt     = (int*)p;    p += (size_t)N_NODES * 4;
    int*   rowptr  = (int*)p;    p += (size_t)N_NODES * 4;
    int*   cur     = (int*)p;    p += (size_t)N_NODES * 4;
    int*   bsum    = (int*)p;    p += 512 * 4;
    int*   boff    = (int*)p;    p += 512 * 4;
    int2*  rec     = (int2*)p;   p += (size_t)N_EDGES * 8;
    float* s01     = (float*)p;  p += (size_t)N_NODES * 128 * 4;
    float* hpr     = (float*)p;  p += (size_t)N_NODES * 64 * 4;

    // ---- CSR build (shared by both layers) ----
    hipMemsetAsync(cnt, 0, (size_t)N_NODES * 4, stream);
    hist_kernel<<<(N_EDGES + 255) / 256, 256, 0, stream>>>(ei, cnt);
    scan_block<<<NB_SCAN, 256, 0, stream>>>(cnt, rowptr, bsum);
    scan_total<<<1, 512, 0, stream>>>(bsum, boff);
    scan_fix<<<NB_SCAN, 256, 0, stream>>>(rowptr, boff, cur);
    scatter_kernel<<<(N_EDGES + 255) / 256, 256, 0, stream>>>(ei, ea, cur, rec);

    // ---- layer 1 ----
    pull_agg<<<(N_NODES * 64) / 256, 256, 0, stream>>>(rowptr, cnt, rec, x, s01);
    gemm_node<64, 1><<<NB_SCAN, 256, 0, stream>>>(s01, x, W1, root1, b1, hpr);

    // ---- layer 2 ----
    pull_agg<<<(N_NODES * 64) / 256, 256, 0, stream>>>(rowptr, cnt, rec, hpr, s01);
    gemm_node<40, 2><<<NB_SCAN, 256, 0, stream>>>(s01, hpr, W2, root2, b2, out);
}

// Round 4
// 418.413 us; speedup vs baseline: 6.5647x; 1.1377x over previous
//
#include <hip/hip_runtime.h>
#include <math.h>

#define N_NODES 100000
#define N_EDGES 1600000
#define NB_SCAN 391  // ceil(N_NODES/256)
#define EPB 4096     // edges per block in filtered scatter
#define NCH 391      // ceil(N_EDGES/EPB)

__device__ __forceinline__ unsigned short f2bf(float f) {
    union { float f; unsigned u; } v; v.f = f;
    unsigned r = v.u + 0x7FFF + ((v.u >> 16) & 1);  // round-nearest-even
    return (unsigned short)(r >> 16);
}
__device__ __forceinline__ float bf2f(unsigned short b) {
    union { unsigned u; float f; } v; v.u = ((unsigned)b) << 16;
    return v.f;
}

// ---------------------------------------------------------------------------
// f32 -> bf16 row copy of x (for the gather path).
// ---------------------------------------------------------------------------
__global__ void x2bf16_kernel(const float* __restrict__ x,
                              unsigned short* __restrict__ xb) {
    int i = blockIdx.x * 256 + threadIdx.x;  // group-of-4 index
    if (i >= N_NODES * 16) return;
    float4 v = reinterpret_cast<const float4*>(x)[i];
    ushort4 o;
    o.x = f2bf(v.x); o.y = f2bf(v.y); o.z = f2bf(v.z); o.w = f2bf(v.w);
    reinterpret_cast<ushort4*>(xb)[i] = o;
}

// ---------------------------------------------------------------------------
// CSR build: histogram of dst, exclusive scan, XCD-partitioned scatter.
// ---------------------------------------------------------------------------
__global__ void hist_kernel(const int* __restrict__ ei, int* __restrict__ cnt) {
    int e = blockIdx.x * 256 + threadIdx.x;
    if (e < N_EDGES) atomicAdd(&cnt[ei[N_EDGES + e]], 1);
}

__global__ void scan_block(const int* __restrict__ cnt, int* __restrict__ rowptr,
                           int* __restrict__ bsum) {
    __shared__ int s[256];
    int i = blockIdx.x * 256 + threadIdx.x;
    int v = (i < N_NODES) ? cnt[i] : 0;
    s[threadIdx.x] = v;
    __syncthreads();
    for (int off = 1; off < 256; off <<= 1) {
        int t = (threadIdx.x >= off) ? s[threadIdx.x - off] : 0;
        __syncthreads();
        s[threadIdx.x] += t;
        __syncthreads();
    }
    if (i < N_NODES) rowptr[i] = s[threadIdx.x] - v;
    if (threadIdx.x == 255) bsum[blockIdx.x] = s[255];
}

__global__ void scan_total(const int* __restrict__ bsum, int* __restrict__ boff) {
    __shared__ int s[512];
    int t = threadIdx.x;
    s[t] = (t < NB_SCAN) ? bsum[t] : 0;
    __syncthreads();
    for (int off = 1; off < 512; off <<= 1) {
        int v = (t >= off) ? s[t - off] : 0;
        __syncthreads();
        s[t] += v;
        __syncthreads();
    }
    boff[t] = (t == 0) ? 0 : s[t - 1];
}

__global__ void scan_fix(int* __restrict__ rowptr, const int* __restrict__ boff,
                         int* __restrict__ cur) {
    int i = blockIdx.x * 256 + threadIdx.x;
    if (i >= N_NODES) return;
    int v = rowptr[i] + boff[blockIdx.x];
    rowptr[i] = v;
    cur[i] = v;
}

// XCD-partitioned scatter: block handles edge chunk (blockIdx>>3), keeps only
// edges with dst/12500 == (blockIdx&7). blockIdx%8 ~ XCD (round-robin), so
// all stores into a given dst bucket come from one XCD's L2 -> full-line
// writebacks instead of 8 partial ones.
__global__ __launch_bounds__(256) void scatter_x(const int* __restrict__ ei,
                                                 const float* __restrict__ ea,
                                                 int* __restrict__ cur,
                                                 int2* __restrict__ rec) {
    int xcd  = blockIdx.x & 7;
    int base = (blockIdx.x >> 3) * EPB;
    for (int i = threadIdx.x; i < EPB; i += 256) {
        int e = base + i;
        if (e >= N_EDGES) break;
        int d = ei[N_EDGES + e];
        if (d / 12500 == xcd) {
            int pos = atomicAdd(&cur[d], 1);
            rec[pos] = make_int2(ei[e], __float_as_int(ea[e]));
        }
    }
}

// ---------------------------------------------------------------------------
// Pull aggregation: one wave per node; 16 lanes per edge (ushort4 = 8B of
// bf16 over 64 feats), 4 edges in flight, shfl_xor cross-group reduce.
// s01[n,0:64] = (1/d)*sum (1-u) feat[src]; s01[n,64:128] = (1/d)*sum u feat[src]
// ---------------------------------------------------------------------------
__global__ __launch_bounds__(256) void pull_agg(
        const int* __restrict__ rowptr, const int* __restrict__ cnt,
        const int2* __restrict__ rec, const unsigned short* __restrict__ featb,
        float* __restrict__ s01) {
    int wid  = (blockIdx.x * 256 + threadIdx.x) >> 6;
    int lane = threadIdx.x & 63;
    if (wid >= N_NODES) return;
    int fg = lane & 15;
    int eg = lane >> 4;
    int start = rowptr[wid];
    int deg   = cnt[wid];
    int end   = start + deg;
    const ushort4* f4 = reinterpret_cast<const ushort4*>(featb);
    float4 a0 = make_float4(0.f, 0.f, 0.f, 0.f);
    float4 a1 = make_float4(0.f, 0.f, 0.f, 0.f);
    for (int i = start + eg; i < end; i += 4) {
        int2 r  = rec[i];
        float u = __int_as_float(r.y);
        ushort4 vb = f4[(size_t)r.x * 16 + fg];
        float vx = bf2f(vb.x), vy = bf2f(vb.y), vz = bf2f(vb.z), vw = bf2f(vb.w);
        float w0 = 1.0f - u;
        a0.x = fmaf(w0, vx, a0.x); a0.y = fmaf(w0, vy, a0.y);
        a0.z = fmaf(w0, vz, a0.z); a0.w = fmaf(w0, vw, a0.w);
        a1.x = fmaf(u, vx, a1.x);  a1.y = fmaf(u, vy, a1.y);
        a1.z = fmaf(u, vz, a1.z);  a1.w = fmaf(u, vw, a1.w);
    }
#define RED4(A)                                             \
    A.x += __shfl_xor(A.x, 16); A.y += __shfl_xor(A.y, 16); \
    A.z += __shfl_xor(A.z, 16); A.w += __shfl_xor(A.w, 16); \
    A.x += __shfl_xor(A.x, 32); A.y += __shfl_xor(A.y, 32); \
    A.z += __shfl_xor(A.z, 32); A.w += __shfl_xor(A.w, 32);
    RED4(a0);
    RED4(a1);
#undef RED4
    float dinv = 1.0f / fmaxf((float)deg, 1.0f);
    float4* o = reinterpret_cast<float4*>(s01) + (size_t)wid * 32;
    if (eg == 0) {
        o[fg] = make_float4(a0.x * dinv, a0.y * dinv, a0.z * dinv, a0.w * dinv);
    } else if (eg == 1) {
        o[16 + fg] = make_float4(a1.x * dinv, a1.y * dinv, a1.z * dinv, a1.w * dinv);
    }
}

// ---------------------------------------------------------------------------
// Node-parallel GEMM: thread = node, COUT accumulators in registers.
// z = [s01(128 f32) | featb(64 bf16)] staged in LDS (XOR-swizzled quads).
// ACT=1: ELU. ACT=2: fused log_softmax. BFOUT=1: bf16 output rows.
// ---------------------------------------------------------------------------
template<int COUT, int ACT, int BFOUT>
__global__ __launch_bounds__(256) void gemm_node(
        const float* __restrict__ s01, const unsigned short* __restrict__ featb,
        const float* __restrict__ W, const float* __restrict__ root,
        const float* __restrict__ bias, void* __restrict__ outv) {
    __shared__ float zt[256 * 65];
    int tid = threadIdx.x;
    int nbase = blockIdx.x * 256;

    float acc[COUT];
#pragma unroll
    for (int c = 0; c < COUT; ++c) acc[c] = 0.0f;

#pragma unroll
    for (int chunk = 0; chunk < 3; ++chunk) {
        __syncthreads();
        if (chunk < 2) {
            int off = chunk * 64;
#pragma unroll 4
            for (int it = 0; it < 16; ++it) {
                int flat = it * 256 + tid;
                int n = flat >> 4;
                int g = flat & 15;
                int gn = nbase + n;
                if (gn >= N_NODES) gn = N_NODES - 1;
                float4 v = *reinterpret_cast<const float4*>(s01 + (size_t)gn * 128 + off + 4 * g);
                *reinterpret_cast<float4*>(zt + n * 64 + 4 * (g ^ (n & 7))) = v;
            }
        } else {
#pragma unroll 4
            for (int it = 0; it < 16; ++it) {
                int flat = it * 256 + tid;
                int n = flat >> 4;
                int g = flat & 15;
                int gn = nbase + n;
                if (gn >= N_NODES) gn = N_NODES - 1;
                ushort4 vb = reinterpret_cast<const ushort4*>(featb)[(size_t)gn * 16 + g];
                float4 v = make_float4(bf2f(vb.x), bf2f(vb.y), bf2f(vb.z), bf2f(vb.w));
                *reinterpret_cast<float4*>(zt + n * 64 + 4 * (g ^ (n & 7))) = v;
            }
        }
        __syncthreads();
        const float* Wc = (chunk < 2) ? (W + chunk * 64 * COUT) : root;
        for (int rq = 0; rq < 16; ++rq) {
            float4 z = *reinterpret_cast<const float4*>(zt + tid * 64 + 4 * (rq ^ (tid & 7)));
            const float* wr = Wc + rq * 4 * COUT;
#pragma unroll
            for (int k = 0; k < 4; ++k) {
                float zk = (k == 0) ? z.x : (k == 1) ? z.y : (k == 2) ? z.z : z.w;
#pragma unroll
                for (int c = 0; c < COUT; ++c)
                    acc[c] = fmaf(zk, wr[k * COUT + c], acc[c]);
            }
        }
    }

#pragma unroll
    for (int c = 0; c < COUT; ++c) acc[c] += bias[c];

    if (ACT == 1) {
#pragma unroll
        for (int c = 0; c < COUT; ++c)
            acc[c] = (acc[c] > 0.0f) ? acc[c] : expm1f(acc[c]);
    } else if (ACT == 2) {
        float m = acc[0];
#pragma unroll
        for (int c = 1; c < COUT; ++c) m = fmaxf(m, acc[c]);
        float s = 0.0f;
#pragma unroll
        for (int c = 0; c < COUT; ++c) s += expf(acc[c] - m);
        float lse = m + logf(s);
#pragma unroll
        for (int c = 0; c < COUT; ++c) acc[c] -= lse;
    }

    // transpose through LDS for coalesced stores
    constexpr int P = COUT + 1;
    __syncthreads();
#pragma unroll
    for (int c = 0; c < COUT; ++c) zt[tid * P + c] = acc[c];
    __syncthreads();
    if (BFOUT) {
        unsigned short* out = (unsigned short*)outv;
        constexpr int CH = COUT / 2;
        for (int it = 0; it < CH; ++it) {
            int flat = it * 256 + tid;
            int n = flat / CH;
            int cp = flat - n * CH;
            int gn = nbase + n;
            if (gn < N_NODES) {
                ushort2 o;
                o.x = f2bf(zt[n * P + 2 * cp]);
                o.y = f2bf(zt[n * P + 2 * cp + 1]);
                *reinterpret_cast<ushort2*>(out + (size_t)gn * COUT + 2 * cp) = o;
            }
        }
    } else {
        float* out = (float*)outv;
        for (int it = 0; it < COUT; ++it) {
            int flat = it * 256 + tid;
            int n = flat / COUT;
            int c = flat - n * COUT;
            int gn = nbase + n;
            if (gn < N_NODES) out[(size_t)gn * COUT + c] = zt[n * P + c];
        }
    }
}

extern "C" void kernel_launch(void* const* d_in, const int* in_sizes, int n_in,
                              void* d_out, int out_size, void* d_ws, size_t ws_size,
                              hipStream_t stream) {
    const float* x     = (const float*)d_in[0];
    const int*   ei    = (const int*)d_in[1];
    const float* ea    = (const float*)d_in[2];
    const float* W1    = (const float*)d_in[3];
    const float* root1 = (const float*)d_in[4];
    const float* b1    = (const float*)d_in[5];
    const float* W2    = (const float*)d_in[6];
    const float* root2 = (const float*)d_in[7];
    const float* b2    = (const float*)d_in[8];
    float* out = (float*)d_out;

    // workspace layout
    char* p = (char*)d_ws;
    int*   cnt     = (int*)p;              p += (size_t)N_NODES * 4;
    int*   rowptr  = (int*)p;              p += (size_t)N_NODES * 4;
    int*   cur     = (int*)p;              p += (size_t)N_NODES * 4;
    int*   bsum    = (int*)p;              p += 512 * 4;
    int*   boff    = (int*)p;              p += 512 * 4;
    int2*  rec     = (int2*)p;             p += (size_t)N_EDGES * 8;
    float* s01     = (float*)p;            p += (size_t)N_NODES * 128 * 4;
    unsigned short* xb   = (unsigned short*)p;  p += (size_t)N_NODES * 64 * 2;
    unsigned short* hprb = (unsigned short*)p;  p += (size_t)N_NODES * 64 * 2;

    // ---- prep ----
    x2bf16_kernel<<<(N_NODES * 16) / 256, 256, 0, stream>>>(x, xb);
    hipMemsetAsync(cnt, 0, (size_t)N_NODES * 4, stream);
    hist_kernel<<<(N_EDGES + 255) / 256, 256, 0, stream>>>(ei, cnt);
    scan_block<<<NB_SCAN, 256, 0, stream>>>(cnt, rowptr, bsum);
    scan_total<<<1, 512, 0, stream>>>(bsum, boff);
    scan_fix<<<NB_SCAN, 256, 0, stream>>>(rowptr, boff, cur);
    scatter_x<<<NCH * 8, 256, 0, stream>>>(ei, ea, cur, rec);

    // ---- layer 1 ----
    pull_agg<<<(N_NODES * 64) / 256, 256, 0, stream>>>(rowptr, cnt, rec, xb, s01);
    gemm_node<64, 1, 1><<<NB_SCAN, 256, 0, stream>>>(s01, xb, W1, root1, b1, hprb);

    // ---- layer 2 ----
    pull_agg<<<(N_NODES * 64) / 256, 256, 0, stream>>>(rowptr, cnt, rec, hprb, s01);
    gemm_node<40, 2, 0><<<NB_SCAN, 256, 0, stream>>>(s01, hprb, W2, root2, b2, out);
}

// Round 5
// 321.459 us; speedup vs baseline: 8.5447x; 1.3016x over previous
//
#include <hip/hip_runtime.h>
#include <math.h>

#define N_NODES 100000
#define N_EDGES 1600000
#define NB_SCAN 391  // ceil(N_NODES/256)
#define EPB 4096     // edges per block in filtered scatter
#define NCH 391      // ceil(N_EDGES/EPB)

typedef __attribute__((ext_vector_type(8))) short bf16x8;
typedef __attribute__((ext_vector_type(4))) float f32x4;

__device__ __forceinline__ unsigned short f2bf(float f) {
    union { float f; unsigned u; } v; v.f = f;
    unsigned r = v.u + 0x7FFF + ((v.u >> 16) & 1);  // round-nearest-even
    return (unsigned short)(r >> 16);
}
__device__ __forceinline__ float bf2f(unsigned short b) {
    union { unsigned u; float f; } v; v.u = ((unsigned)b) << 16;
    return v.f;
}

// ---------------------------------------------------------------------------
// f32 -> bf16 row copy of x (for the gather path).
// ---------------------------------------------------------------------------
__global__ void x2bf16_kernel(const float* __restrict__ x,
                              unsigned short* __restrict__ xb) {
    int i = blockIdx.x * 256 + threadIdx.x;
    if (i >= N_NODES * 16) return;
    float4 v = reinterpret_cast<const float4*>(x)[i];
    ushort4 o;
    o.x = f2bf(v.x); o.y = f2bf(v.y); o.z = f2bf(v.z); o.w = f2bf(v.w);
    reinterpret_cast<ushort4*>(xb)[i] = o;
}

// ---------------------------------------------------------------------------
// Weight transpose+cast: Wt[c][k] (k in 0..191) = {W[0],W[1],root}[k][c], bf16.
// Rows c >= COUT (padding up to CTROWS) are zero.
// ---------------------------------------------------------------------------
__global__ void wt_kernel(const float* __restrict__ W, const float* __restrict__ root,
                          unsigned short* __restrict__ Wt, int COUT, int total) {
    int i = blockIdx.x * 256 + threadIdx.x;
    if (i >= total) return;
    int c = i / 192;
    int k = i - c * 192;
    float v = 0.0f;
    if (c < COUT)
        v = (k < 128) ? W[(k >> 6) * 64 * COUT + (k & 63) * COUT + c]
                      : root[(k - 128) * COUT + c];
    Wt[i] = f2bf(v);
}

// ---------------------------------------------------------------------------
// CSR build: histogram of dst, exclusive scan, XCD-partitioned scatter.
// ---------------------------------------------------------------------------
__global__ void hist_kernel(const int* __restrict__ ei, int* __restrict__ cnt) {
    int e = blockIdx.x * 256 + threadIdx.x;
    if (e < N_EDGES) atomicAdd(&cnt[ei[N_EDGES + e]], 1);
}

__global__ void scan_block(const int* __restrict__ cnt, int* __restrict__ rowptr,
                           int* __restrict__ bsum) {
    __shared__ int s[256];
    int i = blockIdx.x * 256 + threadIdx.x;
    int v = (i < N_NODES) ? cnt[i] : 0;
    s[threadIdx.x] = v;
    __syncthreads();
    for (int off = 1; off < 256; off <<= 1) {
        int t = (threadIdx.x >= off) ? s[threadIdx.x - off] : 0;
        __syncthreads();
        s[threadIdx.x] += t;
        __syncthreads();
    }
    if (i < N_NODES) rowptr[i] = s[threadIdx.x] - v;
    if (threadIdx.x == 255) bsum[blockIdx.x] = s[255];
}

__global__ void scan_total(const int* __restrict__ bsum, int* __restrict__ boff) {
    __shared__ int s[512];
    int t = threadIdx.x;
    s[t] = (t < NB_SCAN) ? bsum[t] : 0;
    __syncthreads();
    for (int off = 1; off < 512; off <<= 1) {
        int v = (t >= off) ? s[t - off] : 0;
        __syncthreads();
        s[t] += v;
        __syncthreads();
    }
    boff[t] = (t == 0) ? 0 : s[t - 1];
}

__global__ void scan_fix(int* __restrict__ rowptr, const int* __restrict__ boff,
                         int* __restrict__ cur) {
    int i = blockIdx.x * 256 + threadIdx.x;
    if (i >= N_NODES) return;
    int v = rowptr[i] + boff[blockIdx.x];
    rowptr[i] = v;
    cur[i] = v;
}

// XCD-partitioned scatter: stores into a given dst bucket region come from
// one XCD's L2 -> full-line writebacks (was 8x write amplification).
__global__ __launch_bounds__(256) void scatter_x(const int* __restrict__ ei,
                                                 const float* __restrict__ ea,
                                                 int* __restrict__ cur,
                                                 int2* __restrict__ rec) {
    int xcd  = blockIdx.x & 7;
    int base = (blockIdx.x >> 3) * EPB;
    for (int i = threadIdx.x; i < EPB; i += 256) {
        int e = base + i;
        if (e >= N_EDGES) break;
        int d = ei[N_EDGES + e];
        if (d / 12500 == xcd) {
            int pos = atomicAdd(&cur[d], 1);
            rec[pos] = make_int2(ei[e], __float_as_int(ea[e]));
        }
    }
}

// ---------------------------------------------------------------------------
// Pull aggregation: one wave per node; 16 lanes per edge (ushort4 = 8B bf16
// over 64 feats), 4 edges in flight, shfl_xor cross-group reduce. Output bf16.
// ---------------------------------------------------------------------------
__global__ __launch_bounds__(256) void pull_agg(
        const int* __restrict__ rowptr, const int* __restrict__ cnt,
        const int2* __restrict__ rec, const unsigned short* __restrict__ featb,
        unsigned short* __restrict__ s01b) {
    int wid  = (blockIdx.x * 256 + threadIdx.x) >> 6;
    int lane = threadIdx.x & 63;
    if (wid >= N_NODES) return;
    int fg = lane & 15;
    int eg = lane >> 4;
    int start = rowptr[wid];
    int deg   = cnt[wid];
    int end   = start + deg;
    const ushort4* f4 = reinterpret_cast<const ushort4*>(featb);
    float4 a0 = make_float4(0.f, 0.f, 0.f, 0.f);
    float4 a1 = make_float4(0.f, 0.f, 0.f, 0.f);
    for (int i = start + eg; i < end; i += 4) {
        int2 r  = rec[i];
        float u = __int_as_float(r.y);
        ushort4 vb = f4[(size_t)r.x * 16 + fg];
        float vx = bf2f(vb.x), vy = bf2f(vb.y), vz = bf2f(vb.z), vw = bf2f(vb.w);
        float w0 = 1.0f - u;
        a0.x = fmaf(w0, vx, a0.x); a0.y = fmaf(w0, vy, a0.y);
        a0.z = fmaf(w0, vz, a0.z); a0.w = fmaf(w0, vw, a0.w);
        a1.x = fmaf(u, vx, a1.x);  a1.y = fmaf(u, vy, a1.y);
        a1.z = fmaf(u, vz, a1.z);  a1.w = fmaf(u, vw, a1.w);
    }
#define RED4(A)                                             \
    A.x += __shfl_xor(A.x, 16); A.y += __shfl_xor(A.y, 16); \
    A.z += __shfl_xor(A.z, 16); A.w += __shfl_xor(A.w, 16); \
    A.x += __shfl_xor(A.x, 32); A.y += __shfl_xor(A.y, 32); \
    A.z += __shfl_xor(A.z, 32); A.w += __shfl_xor(A.w, 32);
    RED4(a0);
    RED4(a1);
#undef RED4
    float dinv = 1.0f / fmaxf((float)deg, 1.0f);
    if (eg == 0) {
        ushort4 o;
        o.x = f2bf(a0.x * dinv); o.y = f2bf(a0.y * dinv);
        o.z = f2bf(a0.z * dinv); o.w = f2bf(a0.w * dinv);
        *reinterpret_cast<ushort4*>(s01b + (size_t)wid * 128 + 4 * fg) = o;
    } else if (eg == 1) {
        ushort4 o;
        o.x = f2bf(a1.x * dinv); o.y = f2bf(a1.y * dinv);
        o.z = f2bf(a1.z * dinv); o.w = f2bf(a1.w * dinv);
        *reinterpret_cast<ushort4*>(s01b + (size_t)wid * 128 + 64 + 4 * fg) = o;
    }
}

// ---------------------------------------------------------------------------
// MFMA node transform. Per block: 256 nodes; wave w owns 64 nodes.
// z[n] = [s01b(128) | featb(64)] bf16 (K=192); Wt is [CT*16][192] bf16.
// Computes D = Wt-frag x z-frag = C^T via mfma_f32_16x16x32_bf16:
//   lane holds node = base + (lane&15); channels ct*16 + (lane>>4)*4 + reg.
// ACT=1: ELU -> bf16 ushort4 stores. ACT=2: fused log_softmax -> f32 out.
// No LDS, no barriers.
// ---------------------------------------------------------------------------
template<int COUT, int CT, int ACT>
__global__ __launch_bounds__(256) void gemm_mfma(
        const unsigned short* __restrict__ s01b,
        const unsigned short* __restrict__ featb,
        const unsigned short* __restrict__ Wt,
        const float* __restrict__ bias, void* __restrict__ outv) {
    int lane = threadIdx.x & 63;
    int wave = threadIdx.x >> 6;
    int l15  = lane & 15;
    int g    = lane >> 4;
    int nodebase = blockIdx.x * 256 + wave * 64;

    f32x4 acc[4][CT];
#pragma unroll
    for (int rt = 0; rt < 4; ++rt)
#pragma unroll
        for (int ct = 0; ct < CT; ++ct) acc[rt][ct] = (f32x4){0.f, 0.f, 0.f, 0.f};

#pragma unroll
    for (int ks = 0; ks < 6; ++ks) {
        int kk = ks * 32 + g * 8;
        bf16x8 zfrag[4];
#pragma unroll
        for (int rt = 0; rt < 4; ++rt) {
            int n = nodebase + rt * 16 + l15;
            if (n >= N_NODES) n = N_NODES - 1;
            const unsigned short* p = (kk < 128)
                ? (s01b + (size_t)n * 128 + kk)
                : (featb + (size_t)n * 64 + (kk - 128));
            zfrag[rt] = *reinterpret_cast<const bf16x8*>(p);
        }
        bf16x8 wfrag[CT];
#pragma unroll
        for (int ct = 0; ct < CT; ++ct)
            wfrag[ct] = *reinterpret_cast<const bf16x8*>(Wt + (size_t)(ct * 16 + l15) * 192 + kk);
#pragma unroll
        for (int rt = 0; rt < 4; ++rt)
#pragma unroll
            for (int ct = 0; ct < CT; ++ct)
                acc[rt][ct] = __builtin_amdgcn_mfma_f32_16x16x32_bf16(
                    wfrag[ct], zfrag[rt], acc[rt][ct], 0, 0, 0);
    }

    // bias per lane: channels ct*16 + g*4 + {0..3}
    f32x4 bv[CT];
#pragma unroll
    for (int ct = 0; ct < CT; ++ct) {
        int base = ct * 16 + g * 4;
        if (base + 4 <= COUT) {
            float4 b = *reinterpret_cast<const float4*>(bias + base);
            bv[ct] = (f32x4){b.x, b.y, b.z, b.w};
        } else {
            bv[ct] = (f32x4){0.f, 0.f, 0.f, 0.f};
        }
    }

    if (ACT == 1) {
        unsigned short* out = (unsigned short*)outv;
#pragma unroll
        for (int rt = 0; rt < 4; ++rt) {
            int n = nodebase + rt * 16 + l15;
            if (n >= N_NODES) continue;
#pragma unroll
            for (int ct = 0; ct < CT; ++ct) {
                f32x4 v = acc[rt][ct] + bv[ct];
                ushort4 o;
                float e;
                e = v[0]; o.x = f2bf(e > 0.f ? e : expm1f(e));
                e = v[1]; o.y = f2bf(e > 0.f ? e : expm1f(e));
                e = v[2]; o.z = f2bf(e > 0.f ? e : expm1f(e));
                e = v[3]; o.w = f2bf(e > 0.f ? e : expm1f(e));
                *reinterpret_cast<ushort4*>(out + (size_t)n * 64 + ct * 16 + g * 4) = o;
            }
        }
    } else {
        float* out = (float*)outv;
#pragma unroll
        for (int rt = 0; rt < 4; ++rt) {
            int n = nodebase + rt * 16 + l15;
            float v[CT * 4];
            float m = -3.4e38f;
#pragma unroll
            for (int ct = 0; ct < CT; ++ct)
#pragma unroll
                for (int r = 0; r < 4; ++r) {
                    int ch = ct * 16 + g * 4 + r;
                    float t = acc[rt][ct][r] + bv[ct][r];
                    v[ct * 4 + r] = t;
                    if (ch < COUT) m = fmaxf(m, t);
                }
            m = fmaxf(m, __shfl_xor(m, 16));
            m = fmaxf(m, __shfl_xor(m, 32));
            float s = 0.0f;
#pragma unroll
            for (int ct = 0; ct < CT; ++ct)
#pragma unroll
                for (int r = 0; r < 4; ++r) {
                    int ch = ct * 16 + g * 4 + r;
                    if (ch < COUT) s += expf(v[ct * 4 + r] - m);
                }
            s += __shfl_xor(s, 16);
            s += __shfl_xor(s, 32);
            float lse = m + logf(s);
            if (n >= N_NODES) continue;
#pragma unroll
            for (int ct = 0; ct < CT; ++ct) {
                int base = ct * 16 + g * 4;
                if (base + 4 <= COUT) {
                    float4 o;
                    o.x = v[ct * 4 + 0] - lse;
                    o.y = v[ct * 4 + 1] - lse;
                    o.z = v[ct * 4 + 2] - lse;
                    o.w = v[ct * 4 + 3] - lse;
                    *reinterpret_cast<float4*>(out + (size_t)n * COUT + base) = o;
                }
            }
        }
    }
}

extern "C" void kernel_launch(void* const* d_in, const int* in_sizes, int n_in,
                              void* d_out, int out_size, void* d_ws, size_t ws_size,
                              hipStream_t stream) {
    const float* x     = (const float*)d_in[0];
    const int*   ei    = (const int*)d_in[1];
    const float* ea    = (const float*)d_in[2];
    const float* W1    = (const float*)d_in[3];
    const float* root1 = (const float*)d_in[4];
    const float* b1    = (const float*)d_in[5];
    const float* W2    = (const float*)d_in[6];
    const float* root2 = (const float*)d_in[7];
    const float* b2    = (const float*)d_in[8];
    float* out = (float*)d_out;

    // workspace layout
    char* p = (char*)d_ws;
    int*   cnt     = (int*)p;              p += (size_t)N_NODES * 4;
    int*   rowptr  = (int*)p;              p += (size_t)N_NODES * 4;
    int*   cur     = (int*)p;              p += (size_t)N_NODES * 4;
    int*   bsum    = (int*)p;              p += 512 * 4;
    int*   boff    = (int*)p;              p += 512 * 4;
    int2*  rec     = (int2*)p;             p += (size_t)N_EDGES * 8;
    unsigned short* s01b = (unsigned short*)p;  p += (size_t)N_NODES * 128 * 2;
    unsigned short* xb   = (unsigned short*)p;  p += (size_t)N_NODES * 64 * 2;
    unsigned short* hprb = (unsigned short*)p;  p += (size_t)N_NODES * 64 * 2;
    unsigned short* Wt1  = (unsigned short*)p;  p += (size_t)64 * 192 * 2;
    unsigned short* Wt2  = (unsigned short*)p;  p += (size_t)48 * 192 * 2;

    // ---- prep ----
    x2bf16_kernel<<<(N_NODES * 16) / 256, 256, 0, stream>>>(x, xb);
    wt_kernel<<<48, 256, 0, stream>>>(W1, root1, Wt1, 64, 64 * 192);
    wt_kernel<<<36, 256, 0, stream>>>(W2, root2, Wt2, 40, 48 * 192);
    hipMemsetAsync(cnt, 0, (size_t)N_NODES * 4, stream);
    hist_kernel<<<(N_EDGES + 255) / 256, 256, 0, stream>>>(ei, cnt);
    scan_block<<<NB_SCAN, 256, 0, stream>>>(cnt, rowptr, bsum);
    scan_total<<<1, 512, 0, stream>>>(bsum, boff);
    scan_fix<<<NB_SCAN, 256, 0, stream>>>(rowptr, boff, cur);
    scatter_x<<<NCH * 8, 256, 0, stream>>>(ei, ea, cur, rec);

    // ---- layer 1 ----
    pull_agg<<<(N_NODES * 64) / 256, 256, 0, stream>>>(rowptr, cnt, rec, xb, s01b);
    gemm_mfma<64, 4, 1><<<NB_SCAN, 256, 0, stream>>>(s01b, xb, Wt1, b1, hprb);

    // ---- layer 2 ----
    pull_agg<<<(N_NODES * 64) / 256, 256, 0, stream>>>(rowptr, cnt, rec, hprb, s01b);
    gemm_mfma<40, 3, 2><<<NB_SCAN, 256, 0, stream>>>(s01b, hprb, Wt2, b2, out);
}

// Round 6
// 214.762 us; speedup vs baseline: 12.7898x; 1.4968x over previous
//
#include <hip/hip_runtime.h>
#include <math.h>

#define N_NODES 100000
#define N_EDGES 1600000
#define NB_SCAN 391   // ceil(N_NODES/256)
#define CHUNK 4096
#define NCHA 391      // ceil(N_EDGES/CHUNK)
#define NBUK 256      // coarse dst buckets
#define DPB 391       // dsts per bucket (256*391 = 100096 >= 100000)
#define BSTRIDE 7168  // per-bucket capacity (mean 6250, sigma ~79)

typedef __attribute__((ext_vector_type(8))) short bf16x8;
typedef __attribute__((ext_vector_type(4))) float f32x4;

__device__ __forceinline__ unsigned short f2bf(float f) {
    union { float f; unsigned u; } v; v.f = f;
    unsigned r = v.u + 0x7FFF + ((v.u >> 16) & 1);  // round-nearest-even
    return (unsigned short)(r >> 16);
}
__device__ __forceinline__ float bf2f(unsigned short b) {
    union { unsigned u; float f; } v; v.u = ((unsigned)b) << 16;
    return v.f;
}

// ---------------------------------------------------------------------------
// f32 -> bf16 row copy of x (for the gather path).
// ---------------------------------------------------------------------------
__global__ void x2bf16_kernel(const float* __restrict__ x,
                              unsigned short* __restrict__ xb) {
    int i = blockIdx.x * 256 + threadIdx.x;
    if (i >= N_NODES * 16) return;
    float4 v = reinterpret_cast<const float4*>(x)[i];
    ushort4 o;
    o.x = f2bf(v.x); o.y = f2bf(v.y); o.z = f2bf(v.z); o.w = f2bf(v.w);
    reinterpret_cast<ushort4*>(xb)[i] = o;
}

// ---------------------------------------------------------------------------
// Weight transpose+cast: Wt[c][k] = {W[0],W[1],root}[k][c], bf16; pad rows 0.
// ---------------------------------------------------------------------------
__global__ void wt_kernel(const float* __restrict__ W, const float* __restrict__ root,
                          unsigned short* __restrict__ Wt, int COUT, int total) {
    int i = blockIdx.x * 256 + threadIdx.x;
    if (i >= total) return;
    int c = i / 192;
    int k = i - c * 192;
    float v = 0.0f;
    if (c < COUT)
        v = (k < 128) ? W[(k >> 6) * 64 * COUT + (k & 63) * COUT + c]
                      : root[(k - 128) * COUT + c];
    Wt[i] = f2bf(v);
}

// ---------------------------------------------------------------------------
// Phase A: bin edges into 256 coarse dst-buckets with LDS compaction, so all
// global writes are contiguous runs (no scattered stores, no XCD reliance).
// Record: {src, u16<<16 | dst_local(10b)}.
// ---------------------------------------------------------------------------
__global__ __launch_bounds__(256) void bin_edges(const int* __restrict__ ei,
                                                 const float* __restrict__ ea,
                                                 int* __restrict__ bucket_cur,
                                                 int2* __restrict__ binned) {
    __shared__ int hist[NBUK];
    __shared__ int lbase[NBUK];
    __shared__ int lcur[NBUK];
    __shared__ int gbase[NBUK];
    __shared__ int2 stage[CHUNK];
    __shared__ unsigned char sbkt[CHUNK];
    int tid = threadIdx.x;
    int e0 = blockIdx.x * CHUNK;
    int nval = min(CHUNK, N_EDGES - e0);

    if (tid < NBUK) hist[tid] = 0;
    __syncthreads();
    for (int j = tid; j < nval; j += 256)
        atomicAdd(&hist[ei[N_EDGES + e0 + j] / DPB], 1);
    __syncthreads();
    // inclusive scan over 256
    if (tid < NBUK) lbase[tid] = hist[tid];
    __syncthreads();
    for (int off = 1; off < NBUK; off <<= 1) {
        int v = (tid < NBUK && tid >= off) ? lbase[tid - off] : 0;
        __syncthreads();
        if (tid < NBUK) lbase[tid] += v;
        __syncthreads();
    }
    if (tid < NBUK) {
        int ex = lbase[tid] - hist[tid];  // exclusive
        lbase[tid] = ex;
        lcur[tid]  = ex;
        gbase[tid] = atomicAdd(&bucket_cur[tid], hist[tid]);
    }
    __syncthreads();
    // compact into LDS grouped by bucket
    for (int j = tid; j < nval; j += 256) {
        int e = e0 + j;
        int d = ei[N_EDGES + e];
        int b = d / DPB;
        int dl = d - b * DPB;
        float u = ea[e];
        int uq = min((int)(u * 65536.0f + 0.5f), 65535);
        int pos = atomicAdd(&lcur[b], 1);
        stage[pos] = make_int2(ei[e], (uq << 16) | dl);
        sbkt[pos] = (unsigned char)b;
    }
    __syncthreads();
    // run-contiguous copy-out
    for (int j = tid; j < nval; j += 256) {
        int b = sbkt[j];
        int gp = gbase[b] + (j - lbase[b]);
        if (gp < BSTRIDE)
            binned[(size_t)b * BSTRIDE + gp] = stage[j];
    }
}

// ---------------------------------------------------------------------------
// Phase B: per-bucket counting sort in LDS. Emits rowptr/cnt (global CSR) and
// dst-sorted rec = {src, u(f32)} with fully coalesced writes.
// ---------------------------------------------------------------------------
__global__ __launch_bounds__(512) void bucket_sort(const int* __restrict__ bucket_cur,
                                                   const int2* __restrict__ binned,
                                                   int2* __restrict__ rec,
                                                   int* __restrict__ rowptr,
                                                   int* __restrict__ cnt_g) {
    __shared__ int cntA[512];
    __shared__ int cntB[512];
    __shared__ int2 stage[BSTRIDE];
    int tid = threadIdx.x;
    int b = blockIdx.x;

    // scan bucket sizes for this bucket's global base
    cntA[tid] = (tid < NBUK) ? bucket_cur[tid] : 0;
    __syncthreads();
    cntB[tid] = cntA[tid];
    __syncthreads();
    for (int off = 1; off < 512; off <<= 1) {
        int v = (tid >= off) ? cntB[tid - off] : 0;
        __syncthreads();
        cntB[tid] += v;
        __syncthreads();
    }
    int base = (b == 0) ? 0 : cntB[b - 1];
    int m = min(cntA[b], BSTRIDE);
    __syncthreads();

    // per-dst histogram over this bucket's 391 dsts
    cntA[tid] = 0;
    __syncthreads();
    const int2* bin = binned + (size_t)b * BSTRIDE;
    for (int j = tid; j < m; j += 512)
        atomicAdd(&cntA[bin[j].y & 1023], 1);
    __syncthreads();
    cntB[tid] = cntA[tid];
    __syncthreads();
    for (int off = 1; off < 512; off <<= 1) {
        int v = (tid >= off) ? cntB[tid - off] : 0;
        __syncthreads();
        cntB[tid] += v;
        __syncthreads();
    }
    // exclusive offsets; emit CSR; init cursors
    {
        int ex = cntB[tid] - cntA[tid];
        int d = b * DPB + tid;
        if (tid < DPB && d < N_NODES) {
            rowptr[d] = base + ex;
            cnt_g[d]  = cntA[tid];
        }
        __syncthreads();
        cntB[tid] = ex;
    }
    __syncthreads();
    // place sorted into LDS
    for (int j = tid; j < m; j += 512) {
        int2 r = bin[j];
        int dl = r.y & 1023;
        float u = ((unsigned)r.y >> 16) * (1.0f / 65536.0f);
        int pos = atomicAdd(&cntB[dl], 1);
        if (pos < BSTRIDE) stage[pos] = make_int2(r.x, __float_as_int(u));
    }
    __syncthreads();
    // coalesced stream-out
    for (int j = tid; j < m; j += 512)
        rec[base + j] = stage[j];
}

// ---------------------------------------------------------------------------
// Pull aggregation: one wave per node; 16 lanes per edge (ushort4 = 8B bf16
// over 64 feats), 4 edges in flight, shfl_xor cross-group reduce. Output bf16.
// ---------------------------------------------------------------------------
__global__ __launch_bounds__(256) void pull_agg(
        const int* __restrict__ rowptr, const int* __restrict__ cnt,
        const int2* __restrict__ rec, const unsigned short* __restrict__ featb,
        unsigned short* __restrict__ s01b) {
    int wid  = (blockIdx.x * 256 + threadIdx.x) >> 6;
    int lane = threadIdx.x & 63;
    if (wid >= N_NODES) return;
    int fg = lane & 15;
    int eg = lane >> 4;
    int start = rowptr[wid];
    int deg   = cnt[wid];
    int end   = start + deg;
    const ushort4* f4 = reinterpret_cast<const ushort4*>(featb);
    float4 a0 = make_float4(0.f, 0.f, 0.f, 0.f);
    float4 a1 = make_float4(0.f, 0.f, 0.f, 0.f);
    for (int i = start + eg; i < end; i += 4) {
        int2 r  = rec[i];
        float u = __int_as_float(r.y);
        ushort4 vb = f4[(size_t)r.x * 16 + fg];
        float vx = bf2f(vb.x), vy = bf2f(vb.y), vz = bf2f(vb.z), vw = bf2f(vb.w);
        float w0 = 1.0f - u;
        a0.x = fmaf(w0, vx, a0.x); a0.y = fmaf(w0, vy, a0.y);
        a0.z = fmaf(w0, vz, a0.z); a0.w = fmaf(w0, vw, a0.w);
        a1.x = fmaf(u, vx, a1.x);  a1.y = fmaf(u, vy, a1.y);
        a1.z = fmaf(u, vz, a1.z);  a1.w = fmaf(u, vw, a1.w);
    }
#define RED4(A)                                             \
    A.x += __shfl_xor(A.x, 16); A.y += __shfl_xor(A.y, 16); \
    A.z += __shfl_xor(A.z, 16); A.w += __shfl_xor(A.w, 16); \
    A.x += __shfl_xor(A.x, 32); A.y += __shfl_xor(A.y, 32); \
    A.z += __shfl_xor(A.z, 32); A.w += __shfl_xor(A.w, 32);
    RED4(a0);
    RED4(a1);
#undef RED4
    float dinv = 1.0f / fmaxf((float)deg, 1.0f);
    if (eg == 0) {
        ushort4 o;
        o.x = f2bf(a0.x * dinv); o.y = f2bf(a0.y * dinv);
        o.z = f2bf(a0.z * dinv); o.w = f2bf(a0.w * dinv);
        *reinterpret_cast<ushort4*>(s01b + (size_t)wid * 128 + 4 * fg) = o;
    } else if (eg == 1) {
        ushort4 o;
        o.x = f2bf(a1.x * dinv); o.y = f2bf(a1.y * dinv);
        o.z = f2bf(a1.z * dinv); o.w = f2bf(a1.w * dinv);
        *reinterpret_cast<ushort4*>(s01b + (size_t)wid * 128 + 64 + 4 * fg) = o;
    }
}

// ---------------------------------------------------------------------------
// MFMA node transform (per block 256 nodes; wave owns 64). K=192 in 6 steps.
// D = Wt-frag x z-frag = C^T: lane holds node = base+(lane&15), channels
// ct*16 + (lane>>4)*4 + reg. ACT=1: ELU->bf16. ACT=2: log_softmax->f32.
// ---------------------------------------------------------------------------
template<int COUT, int CT, int ACT>
__global__ __launch_bounds__(256) void gemm_mfma(
        const unsigned short* __restrict__ s01b,
        const unsigned short* __restrict__ featb,
        const unsigned short* __restrict__ Wt,
        const float* __restrict__ bias, void* __restrict__ outv) {
    int lane = threadIdx.x & 63;
    int wave = threadIdx.x >> 6;
    int l15  = lane & 15;
    int g    = lane >> 4;
    int nodebase = blockIdx.x * 256 + wave * 64;

    f32x4 acc[4][CT];
#pragma unroll
    for (int rt = 0; rt < 4; ++rt)
#pragma unroll
        for (int ct = 0; ct < CT; ++ct) acc[rt][ct] = (f32x4){0.f, 0.f, 0.f, 0.f};

#pragma unroll
    for (int ks = 0; ks < 6; ++ks) {
        int kk = ks * 32 + g * 8;
        bf16x8 zfrag[4];
#pragma unroll
        for (int rt = 0; rt < 4; ++rt) {
            int n = nodebase + rt * 16 + l15;
            if (n >= N_NODES) n = N_NODES - 1;
            const unsigned short* p = (kk < 128)
                ? (s01b + (size_t)n * 128 + kk)
                : (featb + (size_t)n * 64 + (kk - 128));
            zfrag[rt] = *reinterpret_cast<const bf16x8*>(p);
        }
        bf16x8 wfrag[CT];
#pragma unroll
        for (int ct = 0; ct < CT; ++ct)
            wfrag[ct] = *reinterpret_cast<const bf16x8*>(Wt + (size_t)(ct * 16 + l15) * 192 + kk);
#pragma unroll
        for (int rt = 0; rt < 4; ++rt)
#pragma unroll
            for (int ct = 0; ct < CT; ++ct)
                acc[rt][ct] = __builtin_amdgcn_mfma_f32_16x16x32_bf16(
                    wfrag[ct], zfrag[rt], acc[rt][ct], 0, 0, 0);
    }

    f32x4 bv[CT];
#pragma unroll
    for (int ct = 0; ct < CT; ++ct) {
        int base = ct * 16 + g * 4;
        if (base + 4 <= COUT) {
            float4 b = *reinterpret_cast<const float4*>(bias + base);
            bv[ct] = (f32x4){b.x, b.y, b.z, b.w};
        } else {
            bv[ct] = (f32x4){0.f, 0.f, 0.f, 0.f};
        }
    }

    if (ACT == 1) {
        unsigned short* out = (unsigned short*)outv;
#pragma unroll
        for (int rt = 0; rt < 4; ++rt) {
            int n = nodebase + rt * 16 + l15;
            if (n >= N_NODES) continue;
#pragma unroll
            for (int ct = 0; ct < CT; ++ct) {
                f32x4 v = acc[rt][ct] + bv[ct];
                ushort4 o;
                float e;
                e = v[0]; o.x = f2bf(e > 0.f ? e : expm1f(e));
                e = v[1]; o.y = f2bf(e > 0.f ? e : expm1f(e));
                e = v[2]; o.z = f2bf(e > 0.f ? e : expm1f(e));
                e = v[3]; o.w = f2bf(e > 0.f ? e : expm1f(e));
                *reinterpret_cast<ushort4*>(out + (size_t)n * 64 + ct * 16 + g * 4) = o;
            }
        }
    } else {
        float* out = (float*)outv;
#pragma unroll
        for (int rt = 0; rt < 4; ++rt) {
            int n = nodebase + rt * 16 + l15;
            float v[CT * 4];
            float m = -3.4e38f;
#pragma unroll
            for (int ct = 0; ct < CT; ++ct)
#pragma unroll
                for (int r = 0; r < 4; ++r) {
                    int ch = ct * 16 + g * 4 + r;
                    float t = acc[rt][ct][r] + bv[ct][r];
                    v[ct * 4 + r] = t;
                    if (ch < COUT) m = fmaxf(m, t);
                }
            m = fmaxf(m, __shfl_xor(m, 16));
            m = fmaxf(m, __shfl_xor(m, 32));
            float s = 0.0f;
#pragma unroll
            for (int ct = 0; ct < CT; ++ct)
#pragma unroll
                for (int r = 0; r < 4; ++r) {
                    int ch = ct * 16 + g * 4 + r;
                    if (ch < COUT) s += expf(v[ct * 4 + r] - m);
                }
            s += __shfl_xor(s, 16);
            s += __shfl_xor(s, 32);
            float lse = m + logf(s);
            if (n >= N_NODES) continue;
#pragma unroll
            for (int ct = 0; ct < CT; ++ct) {
                int base = ct * 16 + g * 4;
                if (base + 4 <= COUT) {
                    float4 o;
                    o.x = v[ct * 4 + 0] - lse;
                    o.y = v[ct * 4 + 1] - lse;
                    o.z = v[ct * 4 + 2] - lse;
                    o.w = v[ct * 4 + 3] - lse;
                    *reinterpret_cast<float4*>(out + (size_t)n * COUT + base) = o;
                }
            }
        }
    }
}

extern "C" void kernel_launch(void* const* d_in, const int* in_sizes, int n_in,
                              void* d_out, int out_size, void* d_ws, size_t ws_size,
                              hipStream_t stream) {
    const float* x     = (const float*)d_in[0];
    const int*   ei    = (const int*)d_in[1];
    const float* ea    = (const float*)d_in[2];
    const float* W1    = (const float*)d_in[3];
    const float* root1 = (const float*)d_in[4];
    const float* b1    = (const float*)d_in[5];
    const float* W2    = (const float*)d_in[6];
    const float* root2 = (const float*)d_in[7];
    const float* b2    = (const float*)d_in[8];
    float* out = (float*)d_out;

    // workspace layout
    char* p = (char*)d_ws;
    int*   bucket_cur = (int*)p;            p += 512 * 4;
    int2*  binned  = (int2*)p;              p += (size_t)NBUK * BSTRIDE * 8;
    int2*  rec     = (int2*)p;              p += (size_t)N_EDGES * 8;
    int*   rowptr  = (int*)p;               p += (size_t)N_NODES * 4;
    int*   cnt     = (int*)p;               p += (size_t)N_NODES * 4;
    unsigned short* s01b = (unsigned short*)p;  p += (size_t)N_NODES * 128 * 2;
    unsigned short* xb   = (unsigned short*)p;  p += (size_t)N_NODES * 64 * 2;
    unsigned short* hprb = (unsigned short*)p;  p += (size_t)N_NODES * 64 * 2;
    unsigned short* Wt1  = (unsigned short*)p;  p += (size_t)64 * 192 * 2;
    unsigned short* Wt2  = (unsigned short*)p;  p += (size_t)48 * 192 * 2;

    // ---- prep ----
    x2bf16_kernel<<<(N_NODES * 16) / 256, 256, 0, stream>>>(x, xb);
    wt_kernel<<<48, 256, 0, stream>>>(W1, root1, Wt1, 64, 64 * 192);
    wt_kernel<<<36, 256, 0, stream>>>(W2, root2, Wt2, 40, 48 * 192);
    hipMemsetAsync(bucket_cur, 0, 512 * 4, stream);

    // ---- CSR build via 2-phase counting sort (contiguous writes only) ----
    bin_edges<<<NCHA, 256, 0, stream>>>(ei, ea, bucket_cur, binned);
    bucket_sort<<<NBUK, 512, 0, stream>>>(bucket_cur, binned, rec, rowptr, cnt);

    // ---- layer 1 ----
    pull_agg<<<(N_NODES * 64) / 256, 256, 0, stream>>>(rowptr, cnt, rec, xb, s01b);
    gemm_mfma<64, 4, 1><<<NB_SCAN, 256, 0, stream>>>(s01b, xb, Wt1, b1, hprb);

    // ---- layer 2 ----
    pull_agg<<<(N_NODES * 64) / 256, 256, 0, stream>>>(rowptr, cnt, rec, hprb, s01b);
    gemm_mfma<40, 3, 2><<<NB_SCAN, 256, 0, stream>>>(s01b, hprb, Wt2, b2, out);
}